// Round 1
// baseline (1398.235 us; speedup 1.0000x reference)
//
#include <hip/hip_runtime.h>
#include <hip/hip_bf16.h>
#include <math.h>

#define N_TOK 8192
#define D_IN  1024
#define D_H   128

// ---------------------------------------------------------------------------
// Kernel 1: QKV projection, fp32.  out[n][j] = sum_d x[n][d] * W[j][d]
// grid (N/64, 3), block 256.  Tile: 64 rows x 128 cols, BK=32.
// Each thread: 4 rows x 8 cols microtile.
// LDS stride 33 keeps scalar reads at <=2-way bank conflicts (free).
// ---------------------------------------------------------------------------
#define QKV_BM 64
#define QKV_BK 32
#define QKV_LS 33   // LDS leading-dim pad

__global__ __launch_bounds__(256)
void qkv_kernel(const float* __restrict__ x,
                const float* __restrict__ Wq,
                const float* __restrict__ Wk,
                const float* __restrict__ Wv,
                float* __restrict__ qkv)   // [3][N_TOK][D_H]
{
    const float* W = (blockIdx.y == 0) ? Wq : (blockIdx.y == 1) ? Wk : Wv;
    float* out = qkv + (size_t)blockIdx.y * (size_t)N_TOK * D_H;

    __shared__ float xs[QKV_BM][QKV_LS];   // 64 x 33
    __shared__ float ws[D_H][QKV_LS];      // 128 x 33

    const int t  = threadIdx.x;
    const int tx = t & 15;   // col group 0..15  (8 cols each)
    const int ty = t >> 4;   // row group 0..15  (4 rows each)
    const int row0 = blockIdx.x * QKV_BM;

    float acc[4][8] = {};

    for (int k0 = 0; k0 < D_IN; k0 += QKV_BK) {
        // stage x tile: 64*32 floats = 512 float4, 2 per thread (coalesced)
        #pragma unroll
        for (int i = 0; i < 2; ++i) {
            int f4 = t + i * 256;            // 0..511
            int r  = f4 >> 3;                // 8 float4 per row
            int c  = (f4 & 7) << 2;
            float4 v = *(const float4*)&x[(size_t)(row0 + r) * D_IN + k0 + c];
            xs[r][c + 0] = v.x; xs[r][c + 1] = v.y;
            xs[r][c + 2] = v.z; xs[r][c + 3] = v.w;
        }
        // stage W tile: 128*32 floats = 1024 float4, 4 per thread
        #pragma unroll
        for (int i = 0; i < 4; ++i) {
            int f4 = t + i * 256;            // 0..1023
            int r  = f4 >> 3;
            int c  = (f4 & 7) << 2;
            float4 v = *(const float4*)&W[(size_t)r * D_IN + k0 + c];
            ws[r][c + 0] = v.x; ws[r][c + 1] = v.y;
            ws[r][c + 2] = v.z; ws[r][c + 3] = v.w;
        }
        __syncthreads();

        #pragma unroll 8
        for (int kk = 0; kk < QKV_BK; ++kk) {
            float xf[4], wf[8];
            #pragma unroll
            for (int i = 0; i < 4; ++i) xf[i] = xs[ty * 4 + i][kk];
            #pragma unroll
            for (int j = 0; j < 8; ++j) wf[j] = ws[tx * 8 + j][kk];
            #pragma unroll
            for (int i = 0; i < 4; ++i)
                #pragma unroll
                for (int j = 0; j < 8; ++j)
                    acc[i][j] += xf[i] * wf[j];
        }
        __syncthreads();
    }

    #pragma unroll
    for (int i = 0; i < 4; ++i) {
        float4 o0 = make_float4(acc[i][0], acc[i][1], acc[i][2], acc[i][3]);
        float4 o1 = make_float4(acc[i][4], acc[i][5], acc[i][6], acc[i][7]);
        float* dst = &out[(size_t)(row0 + ty * 4 + i) * D_H + tx * 8];
        *(float4*)(dst + 0) = o0;
        *(float4*)(dst + 4) = o1;
    }
}

// ---------------------------------------------------------------------------
// Kernel 2: flash attention, fp32, out = softmax(scale * q k^T) v
// grid N/32 = 256 blocks, block 256 threads.
// BQ=32 q-rows per block, BK=64 keys per tile.
// Thread (ty,tx): S microtile rows {ty*2,ty*2+1} x cols {tx*4..+3};
//                 O microtile rows {ty*2,ty*2+1} x cols {tx*8..+7}.
// Row softmax stats reduced across the 16-lane tx-group via shfl_xor
// (replicated in registers; no LDS stats, no serial pass).
// ---------------------------------------------------------------------------
#define BQ 32
#define BKEY 64
#define QK_LS 132   // 128 + 4: float4-aligned, rows spread 4 banks
#define P_LS  68    // 64 + 4

__global__ __launch_bounds__(256)
void flash_kernel(const float* __restrict__ q,
                  const float* __restrict__ kmat,
                  const float* __restrict__ vmat,
                  float* __restrict__ out)
{
    __shared__ float q_s[BQ][QK_LS];
    __shared__ float k_s[BKEY][QK_LS];
    __shared__ float v_s[BKEY][QK_LS];
    __shared__ float p_s[BQ][P_LS];

    const int t  = threadIdx.x;
    const int tx = t & 15;
    const int ty = t >> 4;
    const int q0 = blockIdx.x * BQ;
    const float scale = 11.313708498984760390f;   // sqrt(128) (MULTIPLY, per ref)

    // stage q tile: 32*128 = 1024 float4, 4 per thread
    #pragma unroll
    for (int i = 0; i < 4; ++i) {
        int f4 = t + i * 256;            // 0..1023
        int r  = f4 >> 5;                // 32 float4 per row
        int c  = (f4 & 31) << 2;
        float4 v = *(const float4*)&q[(size_t)(q0 + r) * D_H + c];
        q_s[r][c + 0] = v.x; q_s[r][c + 1] = v.y;
        q_s[r][c + 2] = v.z; q_s[r][c + 3] = v.w;
    }

    float m_run[2] = { -INFINITY, -INFINITY };
    float l_run[2] = { 0.f, 0.f };
    float o_acc[2][8] = {};

    for (int kt = 0; kt < N_TOK; kt += BKEY) {
        __syncthreads();   // prev PV done (and q_s staged, first iter)
        // stage k,v tiles: each 64*128 = 2048 float4, 8 per thread
        #pragma unroll
        for (int i = 0; i < 8; ++i) {
            int f4 = t + i * 256;          // 0..2047
            int r  = f4 >> 5;
            int c  = (f4 & 31) << 2;
            float4 kv = *(const float4*)&kmat[(size_t)(kt + r) * D_H + c];
            k_s[r][c + 0] = kv.x; k_s[r][c + 1] = kv.y;
            k_s[r][c + 2] = kv.z; k_s[r][c + 3] = kv.w;
            float4 vv = *(const float4*)&vmat[(size_t)(kt + r) * D_H + c];
            v_s[r][c + 0] = vv.x; v_s[r][c + 1] = vv.y;
            v_s[r][c + 2] = vv.z; v_s[r][c + 3] = vv.w;
        }
        __syncthreads();

        // ---- S = scale * q k^T : 2x4 microtile, float4 over d ----
        float s_acc[2][4] = {};
        #pragma unroll 8
        for (int d = 0; d < D_H; d += 4) {
            float4 qa = *(const float4*)&q_s[ty * 2 + 0][d];
            float4 qb = *(const float4*)&q_s[ty * 2 + 1][d];
            #pragma unroll
            for (int j = 0; j < 4; ++j) {
                float4 kf = *(const float4*)&k_s[tx * 4 + j][d];
                s_acc[0][j] += qa.x * kf.x + qa.y * kf.y + qa.z * kf.z + qa.w * kf.w;
                s_acc[1][j] += qb.x * kf.x + qb.y * kf.y + qb.z * kf.z + qb.w * kf.w;
            }
        }
        #pragma unroll
        for (int i = 0; i < 2; ++i)
            #pragma unroll
            for (int j = 0; j < 4; ++j)
                s_acc[i][j] *= scale;

        // ---- online softmax: reduce over 16-lane tx-group ----
        float p[2][4];
        #pragma unroll
        for (int i = 0; i < 2; ++i) {
            float mt = fmaxf(fmaxf(s_acc[i][0], s_acc[i][1]),
                             fmaxf(s_acc[i][2], s_acc[i][3]));
            #pragma unroll
            for (int off = 1; off < 16; off <<= 1)
                mt = fmaxf(mt, __shfl_xor(mt, off, 64));
            float m_new = fmaxf(m_run[i], mt);
            float alpha = __expf(m_run[i] - m_new);   // exp(-inf)=0 first iter
            float rs = 0.f;
            #pragma unroll
            for (int j = 0; j < 4; ++j) {
                p[i][j] = __expf(s_acc[i][j] - m_new);
                rs += p[i][j];
            }
            #pragma unroll
            for (int off = 1; off < 16; off <<= 1)
                rs += __shfl_xor(rs, off, 64);
            l_run[i] = l_run[i] * alpha + rs;
            m_run[i] = m_new;
            #pragma unroll
            for (int j = 0; j < 8; ++j)
                o_acc[i][j] *= alpha;
            *(float4*)&p_s[ty * 2 + i][tx * 4] =
                make_float4(p[i][0], p[i][1], p[i][2], p[i][3]);
        }
        __syncthreads();

        // ---- O += P V ----
        #pragma unroll 8
        for (int kk = 0; kk < BKEY; ++kk) {
            float pa = p_s[ty * 2 + 0][kk];
            float pb = p_s[ty * 2 + 1][kk];
            float4 v0 = *(const float4*)&v_s[kk][tx * 8];
            float4 v1 = *(const float4*)&v_s[kk][tx * 8 + 4];
            o_acc[0][0] += pa * v0.x; o_acc[0][1] += pa * v0.y;
            o_acc[0][2] += pa * v0.z; o_acc[0][3] += pa * v0.w;
            o_acc[0][4] += pa * v1.x; o_acc[0][5] += pa * v1.y;
            o_acc[0][6] += pa * v1.z; o_acc[0][7] += pa * v1.w;
            o_acc[1][0] += pb * v0.x; o_acc[1][1] += pb * v0.y;
            o_acc[1][2] += pb * v0.z; o_acc[1][3] += pb * v0.w;
            o_acc[1][4] += pb * v1.x; o_acc[1][5] += pb * v1.y;
            o_acc[1][6] += pb * v1.z; o_acc[1][7] += pb * v1.w;
        }
    }

    // epilogue: out = O / l
    #pragma unroll
    for (int i = 0; i < 2; ++i) {
        float inv = 1.f / l_run[i];
        float4 o0 = make_float4(o_acc[i][0] * inv, o_acc[i][1] * inv,
                                o_acc[i][2] * inv, o_acc[i][3] * inv);
        float4 o1 = make_float4(o_acc[i][4] * inv, o_acc[i][5] * inv,
                                o_acc[i][6] * inv, o_acc[i][7] * inv);
        float* dst = &out[(size_t)(q0 + ty * 2 + i) * D_H + tx * 8];
        *(float4*)(dst + 0) = o0;
        *(float4*)(dst + 4) = o1;
    }
}

// ---------------------------------------------------------------------------
extern "C" void kernel_launch(void* const* d_in, const int* in_sizes, int n_in,
                              void* d_out, int out_size, void* d_ws, size_t ws_size,
                              hipStream_t stream) {
    const float* x  = (const float*)d_in[0];
    const float* Wq = (const float*)d_in[1];
    const float* Wk = (const float*)d_in[2];
    const float* Wv = (const float*)d_in[3];
    float* out = (float*)d_out;

    // workspace: q,k,v fp32 = 3 * 8192 * 128 * 4 B = 12.6 MB
    float* qkv = (float*)d_ws;
    float* qp = qkv;
    float* kp = qkv + (size_t)N_TOK * D_H;
    float* vp = qkv + 2 * (size_t)N_TOK * D_H;

    qkv_kernel<<<dim3(N_TOK / QKV_BM, 3), 256, 0, stream>>>(x, Wq, Wk, Wv, qkv);
    flash_kernel<<<dim3(N_TOK / BQ), 256, 0, stream>>>(qp, kp, vp, out);
}

// Round 2
// 795.642 us; speedup vs baseline: 1.7574x; 1.7574x over previous
//
#include <hip/hip_runtime.h>
#include <hip/hip_bf16.h>
#include <math.h>

#define N_TOK 8192
#define D_IN  1024
#define D_H   128

typedef __bf16 bf16;
typedef __attribute__((ext_vector_type(8))) __bf16 bf16x8;
typedef __attribute__((ext_vector_type(4))) float floatx4;

#define MFMA16(a, b, c) __builtin_amdgcn_mfma_f32_16x16x32_bf16((a), (b), (c), 0, 0, 0)

// ---------------------------------------------------------------------------
// Kernel 1: QKV projection, fp32 accumulate; epilogue emits split-bf16.
//   y==0: q_hi/q_lo = split(sqrt(128) * x@Wq^T)   (scale folded into q)
//   y==1: k_hi/k_lo = split(x@Wk^T)
//   y==2: vt        = bf16(x@Wv^T) TRANSPOSED [D_H][N_TOK]
// grid (128, 3), block 256. Tile 64x128, BK=32, 4x8 microtile/thread.
// ---------------------------------------------------------------------------
#define QKV_BM 64
#define QKV_BK 32
#define QKV_LS 33

__global__ __launch_bounds__(256)
void qkv_kernel(const float* __restrict__ x,
                const float* __restrict__ Wq,
                const float* __restrict__ Wk,
                const float* __restrict__ Wv,
                bf16* __restrict__ q_hi, bf16* __restrict__ q_lo,
                bf16* __restrict__ k_hi, bf16* __restrict__ k_lo,
                bf16* __restrict__ vt)
{
    const float* W = (blockIdx.y == 0) ? Wq : (blockIdx.y == 1) ? Wk : Wv;

    __shared__ float xs[QKV_BM][QKV_LS];
    __shared__ float ws[D_H][QKV_LS];

    const int t  = threadIdx.x;
    const int tx = t & 15;
    const int ty = t >> 4;
    const int row0 = blockIdx.x * QKV_BM;

    float acc[4][8] = {};

    for (int k0 = 0; k0 < D_IN; k0 += QKV_BK) {
        #pragma unroll
        for (int i = 0; i < 2; ++i) {
            int f4 = t + i * 256;
            int r  = f4 >> 3;
            int c  = (f4 & 7) << 2;
            float4 v = *(const float4*)&x[(size_t)(row0 + r) * D_IN + k0 + c];
            xs[r][c + 0] = v.x; xs[r][c + 1] = v.y;
            xs[r][c + 2] = v.z; xs[r][c + 3] = v.w;
        }
        #pragma unroll
        for (int i = 0; i < 4; ++i) {
            int f4 = t + i * 256;
            int r  = f4 >> 3;
            int c  = (f4 & 7) << 2;
            float4 v = *(const float4*)&W[(size_t)r * D_IN + k0 + c];
            ws[r][c + 0] = v.x; ws[r][c + 1] = v.y;
            ws[r][c + 2] = v.z; ws[r][c + 3] = v.w;
        }
        __syncthreads();

        #pragma unroll 8
        for (int kk = 0; kk < QKV_BK; ++kk) {
            float xf[4], wf[8];
            #pragma unroll
            for (int i = 0; i < 4; ++i) xf[i] = xs[ty * 4 + i][kk];
            #pragma unroll
            for (int j = 0; j < 8; ++j) wf[j] = ws[tx * 8 + j][kk];
            #pragma unroll
            for (int i = 0; i < 4; ++i)
                #pragma unroll
                for (int j = 0; j < 8; ++j)
                    acc[i][j] += xf[i] * wf[j];
        }
        __syncthreads();
    }

    if (blockIdx.y <= 1) {
        bf16* hi_out = (blockIdx.y == 0) ? q_hi : k_hi;
        bf16* lo_out = (blockIdx.y == 0) ? q_lo : k_lo;
        const float sc = (blockIdx.y == 0) ? 11.313708498984760390f : 1.0f;
        #pragma unroll
        for (int i = 0; i < 4; ++i) {
            bf16x8 hv, lv;
            #pragma unroll
            for (int j = 0; j < 8; ++j) {
                float a = acc[i][j] * sc;
                bf16 h = (bf16)a;
                hv[j] = h;
                lv[j] = (bf16)(a - (float)h);
            }
            int row = row0 + ty * 4 + i;
            *(bf16x8*)&hi_out[(size_t)row * D_H + tx * 8] = hv;
            *(bf16x8*)&lo_out[(size_t)row * D_H + tx * 8] = lv;
        }
    } else {
        // transposed store vt[d][n] (scattered 2B; 2 MB once — cheap)
        #pragma unroll
        for (int i = 0; i < 4; ++i)
            #pragma unroll
            for (int j = 0; j < 8; ++j)
                vt[(size_t)(tx * 8 + j) * N_TOK + row0 + ty * 4 + i] = (bf16)acc[i][j];
    }
}

// ---------------------------------------------------------------------------
// Kernel 2: flash attention with split-bf16 MFMA.
// grid 128 blocks (BQ=64), 256 threads = 4 waves; wave w owns q-rows
// w*16..w*16+15 and iterates ALL keys (softmax stats wave-private).
// Per key-tile (BKEY=64): S = Qhi*Kh + Qlo*Kh + Qhi*Kl (3-pass MFMA),
// online softmax on C-layout regs (shfl over 16 lanes), P -> LDS (bf16,
// wave-private, no barrier), O += P*V via MFMA with V^T tiles.
// Staging software-pipelined one iter ahead through registers.
// ---------------------------------------------------------------------------
#define BQ   64
#define BKEY 64
#define KLS  136   // 128 + 8 bf16: row stride 272 B -> bank advance 4/row, 2-way max
#define VLS  72    // 64 + 8
#define PLS  72

__global__ __launch_bounds__(256, 1)
void flash_kernel(const bf16* __restrict__ qh, const bf16* __restrict__ ql,
                  const bf16* __restrict__ kh, const bf16* __restrict__ kl,
                  const bf16* __restrict__ vt, float* __restrict__ out)
{
    __shared__ bf16 kh_s[BKEY][KLS];
    __shared__ bf16 kl_s[BKEY][KLS];
    __shared__ bf16 vt_s[D_H][VLS];
    __shared__ bf16 p_s[BQ][PLS];

    const int t    = threadIdx.x;
    const int lane = t & 63;
    const int wid  = t >> 6;           // 0..3
    const int lid  = lane & 15;
    const int quad = lane >> 4;        // 0..3
    const int q0   = blockIdx.x * BQ;
    const int strip = wid * 16;

    // ---- preload Q fragments (block-resident, scale pre-folded) ----
    bf16x8 a_hi[4], a_lo[4];
    {
        const size_t rowb = (size_t)(q0 + strip + lid) * D_H + quad * 8;
        #pragma unroll
        for (int kc = 0; kc < 4; ++kc) {
            a_hi[kc] = *(const bf16x8*)(qh + rowb + kc * 32);
            a_lo[kc] = *(const bf16x8*)(ql + rowb + kc * 32);
        }
    }

    float m_run[4] = { -INFINITY, -INFINITY, -INFINITY, -INFINITY };
    float l_run[4] = { 0.f, 0.f, 0.f, 0.f };
    floatx4 o_acc[8];
    #pragma unroll
    for (int ct = 0; ct < 8; ++ct)
        #pragma unroll
        for (int r = 0; r < 4; ++r) o_acc[ct][r] = 0.f;

    uint4 rkh[4], rkl[4], rv[4];
    auto load_tiles = [&](int kt) {
        #pragma unroll
        for (int i = 0; i < 4; ++i) {
            int idx  = t + i * 256;          // 0..1023
            int key  = idx >> 4, coff = (idx & 15) << 3;
            int d    = idx >> 3, koff = (idx & 7) << 3;
            rkh[i] = *(const uint4*)(kh + (size_t)(kt + key) * D_H + coff);
            rkl[i] = *(const uint4*)(kl + (size_t)(kt + key) * D_H + coff);
            rv[i]  = *(const uint4*)(vt + (size_t)d * N_TOK + kt + koff);
        }
    };

    load_tiles(0);

    for (int kt = 0; kt < N_TOK; kt += BKEY) {
        __syncthreads();                       // prev iter's LDS consumers done
        #pragma unroll
        for (int i = 0; i < 4; ++i) {
            int idx  = t + i * 256;
            int key  = idx >> 4, coff = (idx & 15) << 3;
            int d    = idx >> 3, koff = (idx & 7) << 3;
            *(uint4*)&kh_s[key][coff] = rkh[i];
            *(uint4*)&kl_s[key][coff] = rkl[i];
            *(uint4*)&vt_s[d][koff]   = rv[i];
        }
        __syncthreads();
        if (kt + BKEY < N_TOK) load_tiles(kt + BKEY);   // prefetch next iter

        // ---- S = (scaled q) . k^T, split-bf16 3-pass ----
        floatx4 s[4];
        #pragma unroll
        for (int ct = 0; ct < 4; ++ct)
            #pragma unroll
            for (int r = 0; r < 4; ++r) s[ct][r] = 0.f;

        #pragma unroll
        for (int kc = 0; kc < 4; ++kc) {
            #pragma unroll
            for (int ct = 0; ct < 4; ++ct) {
                bf16x8 bh = *(const bf16x8*)&kh_s[ct * 16 + lid][kc * 32 + quad * 8];
                bf16x8 bl = *(const bf16x8*)&kl_s[ct * 16 + lid][kc * 32 + quad * 8];
                s[ct] = MFMA16(a_hi[kc], bh, s[ct]);
                s[ct] = MFMA16(a_lo[kc], bh, s[ct]);
                s[ct] = MFMA16(a_hi[kc], bl, s[ct]);
            }
        }

        // ---- online softmax (rows = strip + quad*4 + r, cols across 16 lanes) ----
        float alpha[4];
        float p[4][4];
        #pragma unroll
        for (int r = 0; r < 4; ++r) {
            float m = fmaxf(fmaxf(s[0][r], s[1][r]), fmaxf(s[2][r], s[3][r]));
            #pragma unroll
            for (int off = 1; off < 16; off <<= 1)
                m = fmaxf(m, __shfl_xor(m, off, 64));
            float mn = fmaxf(m_run[r], m);
            alpha[r] = __expf(m_run[r] - mn);   // exp(-inf)=0 first iter
            m_run[r] = mn;
            float rs = 0.f;
            #pragma unroll
            for (int ct = 0; ct < 4; ++ct) {
                p[r][ct] = __expf(s[ct][r] - mn);
                rs += p[r][ct];
            }
            #pragma unroll
            for (int off = 1; off < 16; off <<= 1)
                rs += __shfl_xor(rs, off, 64);
            l_run[r] = l_run[r] * alpha[r] + rs;
        }

        // P -> LDS in A-layout source (row-major), wave-private strip
        #pragma unroll
        for (int r = 0; r < 4; ++r)
            #pragma unroll
            for (int ct = 0; ct < 4; ++ct)
                p_s[strip + quad * 4 + r][ct * 16 + lid] = (bf16)p[r][ct];

        // rescale O
        #pragma unroll
        for (int ct = 0; ct < 8; ++ct)
            #pragma unroll
            for (int r = 0; r < 4; ++r)
                o_acc[ct][r] *= alpha[r];

        // ---- O += P V ----
        #pragma unroll
        for (int kc2 = 0; kc2 < 2; ++kc2) {
            bf16x8 ap = *(const bf16x8*)&p_s[strip + lid][kc2 * 32 + quad * 8];
            #pragma unroll
            for (int ct = 0; ct < 8; ++ct) {
                bf16x8 bv = *(const bf16x8*)&vt_s[ct * 16 + lid][kc2 * 32 + quad * 8];
                o_acc[ct] = MFMA16(ap, bv, o_acc[ct]);
            }
        }
    }

    // ---- epilogue: out = O / l ----
    float inv[4];
    #pragma unroll
    for (int r = 0; r < 4; ++r) inv[r] = 1.f / l_run[r];
    #pragma unroll
    for (int ct = 0; ct < 8; ++ct)
        #pragma unroll
        for (int r = 0; r < 4; ++r)
            out[(size_t)(q0 + strip + quad * 4 + r) * D_H + ct * 16 + lid] =
                o_acc[ct][r] * inv[r];
}

// ---------------------------------------------------------------------------
extern "C" void kernel_launch(void* const* d_in, const int* in_sizes, int n_in,
                              void* d_out, int out_size, void* d_ws, size_t ws_size,
                              hipStream_t stream) {
    const float* x  = (const float*)d_in[0];
    const float* Wq = (const float*)d_in[1];
    const float* Wk = (const float*)d_in[2];
    const float* Wv = (const float*)d_in[3];
    float* out = (float*)d_out;

    // ws (bf16): q_hi, q_lo, k_hi, k_lo [N][D_H] row-major; vt [D_H][N]. 10 MB.
    bf16* ws = (bf16*)d_ws;
    const size_t SZ = (size_t)N_TOK * D_H;
    bf16* qh = ws;
    bf16* ql = ws + SZ;
    bf16* kh = ws + 2 * SZ;
    bf16* kl = ws + 3 * SZ;
    bf16* vt = ws + 4 * SZ;

    qkv_kernel<<<dim3(N_TOK / QKV_BM, 3), 256, 0, stream>>>(x, Wq, Wk, Wv,
                                                            qh, ql, kh, kl, vt);
    flash_kernel<<<dim3(N_TOK / BQ), 256, 0, stream>>>(qh, ql, kh, kl, vt, out);
}

// Round 3
// 512.663 us; speedup vs baseline: 2.7274x; 1.5520x over previous
//
#include <hip/hip_runtime.h>
#include <hip/hip_bf16.h>
#include <math.h>

#define N_TOK 8192
#define D_IN  1024
#define D_H   128
#define SPLIT 4                      // key-splits across blocks
#define SPAN  (N_TOK / SPLIT)        // 2048 keys per block

typedef __bf16 bf16;
typedef __attribute__((ext_vector_type(8))) __bf16 bf16x8;
typedef __attribute__((ext_vector_type(4))) float floatx4;

#define MFMA16(a, b, c) __builtin_amdgcn_mfma_f32_16x16x32_bf16((a), (b), (c), 0, 0, 0)

// ---------------------------------------------------------------------------
// Kernel 1: QKV projection, fp32 accumulate; epilogue emits split-bf16.
// (unchanged from round 2 — optimize next round)
// ---------------------------------------------------------------------------
#define QKV_BM 64
#define QKV_BK 32
#define QKV_LS 33

__global__ __launch_bounds__(256)
void qkv_kernel(const float* __restrict__ x,
                const float* __restrict__ Wq,
                const float* __restrict__ Wk,
                const float* __restrict__ Wv,
                bf16* __restrict__ q_hi, bf16* __restrict__ q_lo,
                bf16* __restrict__ k_hi, bf16* __restrict__ k_lo,
                bf16* __restrict__ vt)
{
    const float* W = (blockIdx.y == 0) ? Wq : (blockIdx.y == 1) ? Wk : Wv;

    __shared__ float xs[QKV_BM][QKV_LS];
    __shared__ float ws[D_H][QKV_LS];

    const int t  = threadIdx.x;
    const int tx = t & 15;
    const int ty = t >> 4;
    const int row0 = blockIdx.x * QKV_BM;

    float acc[4][8] = {};

    for (int k0 = 0; k0 < D_IN; k0 += QKV_BK) {
        #pragma unroll
        for (int i = 0; i < 2; ++i) {
            int f4 = t + i * 256;
            int r  = f4 >> 3;
            int c  = (f4 & 7) << 2;
            float4 v = *(const float4*)&x[(size_t)(row0 + r) * D_IN + k0 + c];
            xs[r][c + 0] = v.x; xs[r][c + 1] = v.y;
            xs[r][c + 2] = v.z; xs[r][c + 3] = v.w;
        }
        #pragma unroll
        for (int i = 0; i < 4; ++i) {
            int f4 = t + i * 256;
            int r  = f4 >> 3;
            int c  = (f4 & 7) << 2;
            float4 v = *(const float4*)&W[(size_t)r * D_IN + k0 + c];
            ws[r][c + 0] = v.x; ws[r][c + 1] = v.y;
            ws[r][c + 2] = v.z; ws[r][c + 3] = v.w;
        }
        __syncthreads();

        #pragma unroll 8
        for (int kk = 0; kk < QKV_BK; ++kk) {
            float xf[4], wf[8];
            #pragma unroll
            for (int i = 0; i < 4; ++i) xf[i] = xs[ty * 4 + i][kk];
            #pragma unroll
            for (int j = 0; j < 8; ++j) wf[j] = ws[tx * 8 + j][kk];
            #pragma unroll
            for (int i = 0; i < 4; ++i)
                #pragma unroll
                for (int j = 0; j < 8; ++j)
                    acc[i][j] += xf[i] * wf[j];
        }
        __syncthreads();
    }

    if (blockIdx.y <= 1) {
        bf16* hi_out = (blockIdx.y == 0) ? q_hi : k_hi;
        bf16* lo_out = (blockIdx.y == 0) ? q_lo : k_lo;
        const float sc = (blockIdx.y == 0) ? 11.313708498984760390f : 1.0f;
        #pragma unroll
        for (int i = 0; i < 4; ++i) {
            bf16x8 hv, lv;
            #pragma unroll
            for (int j = 0; j < 8; ++j) {
                float a = acc[i][j] * sc;
                bf16 h = (bf16)a;
                hv[j] = h;
                lv[j] = (bf16)(a - (float)h);
            }
            int row = row0 + ty * 4 + i;
            *(bf16x8*)&hi_out[(size_t)row * D_H + tx * 8] = hv;
            *(bf16x8*)&lo_out[(size_t)row * D_H + tx * 8] = lv;
        }
    } else {
        #pragma unroll
        for (int i = 0; i < 4; ++i)
            #pragma unroll
            for (int j = 0; j < 8; ++j)
                vt[(size_t)(tx * 8 + j) * N_TOK + row0 + ty * 4 + i] = (bf16)acc[i][j];
    }
}

// ---------------------------------------------------------------------------
// Kernel 2: flash attention, split-bf16 MFMA, KEY-SPLIT across blocks.
// grid (N/BQ, SPLIT) = (128, 4) = 512 blocks -> 2 blocks/CU on all 256 CUs.
// Block (x, s) handles q-rows x*64.. and keys [s*2048, (s+1)*2048), writing
// unnormalized O and per-row (m, l) partials; combine_kernel merges.
// ---------------------------------------------------------------------------
#define BQ   64
#define BKEY 64
#define KLS  136
#define VLS  72
#define PLS  72

__global__ __launch_bounds__(256, 1)
void flash_kernel(const bf16* __restrict__ qh, const bf16* __restrict__ ql,
                  const bf16* __restrict__ kh, const bf16* __restrict__ kl,
                  const bf16* __restrict__ vt,
                  float* __restrict__ opart,   // [SPLIT][N][D_H]
                  float* __restrict__ mpart,   // [SPLIT][N]
                  float* __restrict__ lpart)   // [SPLIT][N]
{
    __shared__ bf16 kh_s[BKEY][KLS];
    __shared__ bf16 kl_s[BKEY][KLS];
    __shared__ bf16 vt_s[D_H][VLS];
    __shared__ bf16 p_s[BQ][PLS];

    const int t    = threadIdx.x;
    const int lane = t & 63;
    const int wid  = t >> 6;
    const int lid  = lane & 15;
    const int quad = lane >> 4;
    const int q0   = blockIdx.x * BQ;
    const int strip = wid * 16;
    const int base  = blockIdx.y * SPAN;

    bf16x8 a_hi[4], a_lo[4];
    {
        const size_t rowb = (size_t)(q0 + strip + lid) * D_H + quad * 8;
        #pragma unroll
        for (int kc = 0; kc < 4; ++kc) {
            a_hi[kc] = *(const bf16x8*)(qh + rowb + kc * 32);
            a_lo[kc] = *(const bf16x8*)(ql + rowb + kc * 32);
        }
    }

    float m_run[4] = { -INFINITY, -INFINITY, -INFINITY, -INFINITY };
    float l_run[4] = { 0.f, 0.f, 0.f, 0.f };
    floatx4 o_acc[8];
    #pragma unroll
    for (int ct = 0; ct < 8; ++ct)
        #pragma unroll
        for (int r = 0; r < 4; ++r) o_acc[ct][r] = 0.f;

    uint4 rkh[4], rkl[4], rv[4];
    auto load_tiles = [&](int kt) {
        #pragma unroll
        for (int i = 0; i < 4; ++i) {
            int idx  = t + i * 256;
            int key  = idx >> 4, coff = (idx & 15) << 3;
            int d    = idx >> 3, koff = (idx & 7) << 3;
            rkh[i] = *(const uint4*)(kh + (size_t)(kt + key) * D_H + coff);
            rkl[i] = *(const uint4*)(kl + (size_t)(kt + key) * D_H + coff);
            rv[i]  = *(const uint4*)(vt + (size_t)d * N_TOK + kt + koff);
        }
    };

    load_tiles(base);

    for (int kt = base; kt < base + SPAN; kt += BKEY) {
        __syncthreads();
        #pragma unroll
        for (int i = 0; i < 4; ++i) {
            int idx  = t + i * 256;
            int key  = idx >> 4, coff = (idx & 15) << 3;
            int d    = idx >> 3, koff = (idx & 7) << 3;
            *(uint4*)&kh_s[key][coff] = rkh[i];
            *(uint4*)&kl_s[key][coff] = rkl[i];
            *(uint4*)&vt_s[d][koff]   = rv[i];
        }
        __syncthreads();
        if (kt + BKEY < base + SPAN) load_tiles(kt + BKEY);

        // ---- S = (scaled q) . k^T, split-bf16 3-pass ----
        floatx4 s[4];
        #pragma unroll
        for (int ct = 0; ct < 4; ++ct)
            #pragma unroll
            for (int r = 0; r < 4; ++r) s[ct][r] = 0.f;

        #pragma unroll
        for (int kc = 0; kc < 4; ++kc) {
            #pragma unroll
            for (int ct = 0; ct < 4; ++ct) {
                bf16x8 bh = *(const bf16x8*)&kh_s[ct * 16 + lid][kc * 32 + quad * 8];
                bf16x8 bl = *(const bf16x8*)&kl_s[ct * 16 + lid][kc * 32 + quad * 8];
                s[ct] = MFMA16(a_hi[kc], bh, s[ct]);
                s[ct] = MFMA16(a_lo[kc], bh, s[ct]);
                s[ct] = MFMA16(a_hi[kc], bl, s[ct]);
            }
        }

        // ---- online softmax ----
        float alpha[4];
        float p[4][4];
        #pragma unroll
        for (int r = 0; r < 4; ++r) {
            float m = fmaxf(fmaxf(s[0][r], s[1][r]), fmaxf(s[2][r], s[3][r]));
            #pragma unroll
            for (int off = 1; off < 16; off <<= 1)
                m = fmaxf(m, __shfl_xor(m, off, 64));
            float mn = fmaxf(m_run[r], m);
            alpha[r] = __expf(m_run[r] - mn);
            m_run[r] = mn;
            float rs = 0.f;
            #pragma unroll
            for (int ct = 0; ct < 4; ++ct) {
                p[r][ct] = __expf(s[ct][r] - mn);
                rs += p[r][ct];
            }
            #pragma unroll
            for (int off = 1; off < 16; off <<= 1)
                rs += __shfl_xor(rs, off, 64);
            l_run[r] = l_run[r] * alpha[r] + rs;
        }

        #pragma unroll
        for (int r = 0; r < 4; ++r)
            #pragma unroll
            for (int ct = 0; ct < 4; ++ct)
                p_s[strip + quad * 4 + r][ct * 16 + lid] = (bf16)p[r][ct];

        #pragma unroll
        for (int ct = 0; ct < 8; ++ct)
            #pragma unroll
            for (int r = 0; r < 4; ++r)
                o_acc[ct][r] *= alpha[r];

        // ---- O += P V ----
        #pragma unroll
        for (int kc2 = 0; kc2 < 2; ++kc2) {
            bf16x8 ap = *(const bf16x8*)&p_s[strip + lid][kc2 * 32 + quad * 8];
            #pragma unroll
            for (int ct = 0; ct < 8; ++ct) {
                bf16x8 bv = *(const bf16x8*)&vt_s[ct * 16 + lid][kc2 * 32 + quad * 8];
                o_acc[ct] = MFMA16(ap, bv, o_acc[ct]);
            }
        }
    }

    // ---- epilogue: write unnormalized partials ----
    float* op = opart + (size_t)blockIdx.y * N_TOK * D_H;
    #pragma unroll
    for (int ct = 0; ct < 8; ++ct)
        #pragma unroll
        for (int r = 0; r < 4; ++r)
            op[(size_t)(q0 + strip + quad * 4 + r) * D_H + ct * 16 + lid] =
                o_acc[ct][r];
    if (lid == 0) {
        #pragma unroll
        for (int r = 0; r < 4; ++r) {
            int row = q0 + strip + quad * 4 + r;
            mpart[(size_t)blockIdx.y * N_TOK + row] = m_run[r];
            lpart[(size_t)blockIdx.y * N_TOK + row] = l_run[r];
        }
    }
}

// ---------------------------------------------------------------------------
// Kernel 3: merge the SPLIT partials.
// grid N/16 = 512 blocks, 256 threads; 16-lane group per row, 8 cols/lane.
// ---------------------------------------------------------------------------
__global__ __launch_bounds__(256)
void combine_kernel(const float* __restrict__ opart,
                    const float* __restrict__ mpart,
                    const float* __restrict__ lpart,
                    float* __restrict__ out)
{
    const int t   = threadIdx.x;
    const int row = blockIdx.x * 16 + (t >> 4);
    const int c0  = (t & 15) * 8;

    float ms[SPLIT], ls[SPLIT];
    float mstar = -INFINITY;
    #pragma unroll
    for (int s = 0; s < SPLIT; ++s) {
        ms[s] = mpart[(size_t)s * N_TOK + row];
        ls[s] = lpart[(size_t)s * N_TOK + row];
        mstar = fmaxf(mstar, ms[s]);
    }
    float4 acc0 = make_float4(0.f, 0.f, 0.f, 0.f);
    float4 acc1 = make_float4(0.f, 0.f, 0.f, 0.f);
    float L = 0.f;
    #pragma unroll
    for (int s = 0; s < SPLIT; ++s) {
        float w = __expf(ms[s] - mstar);
        L += w * ls[s];
        const float* p = &opart[((size_t)s * N_TOK + row) * D_H + c0];
        float4 a = *(const float4*)(p + 0);
        float4 b = *(const float4*)(p + 4);
        acc0.x += w * a.x; acc0.y += w * a.y; acc0.z += w * a.z; acc0.w += w * a.w;
        acc1.x += w * b.x; acc1.y += w * b.y; acc1.z += w * b.z; acc1.w += w * b.w;
    }
    float inv = 1.f / L;
    float* dst = &out[(size_t)row * D_H + c0];
    *(float4*)(dst + 0) = make_float4(acc0.x * inv, acc0.y * inv,
                                      acc0.z * inv, acc0.w * inv);
    *(float4*)(dst + 4) = make_float4(acc1.x * inv, acc1.y * inv,
                                      acc1.z * inv, acc1.w * inv);
}

// ---------------------------------------------------------------------------
extern "C" void kernel_launch(void* const* d_in, const int* in_sizes, int n_in,
                              void* d_out, int out_size, void* d_ws, size_t ws_size,
                              hipStream_t stream) {
    const float* x  = (const float*)d_in[0];
    const float* Wq = (const float*)d_in[1];
    const float* Wk = (const float*)d_in[2];
    const float* Wv = (const float*)d_in[3];
    float* out = (float*)d_out;

    // ws layout: bf16 qh,ql,kh,kl [N][128], vt [128][N]  (10 MB)
    //            fp32 opart [SPLIT][N][128] (16 MB), mpart/lpart [SPLIT][N]
    bf16* wsb = (bf16*)d_ws;
    const size_t SZ = (size_t)N_TOK * D_H;
    bf16* qh = wsb;
    bf16* ql = wsb + SZ;
    bf16* kh = wsb + 2 * SZ;
    bf16* kl = wsb + 3 * SZ;
    bf16* vt = wsb + 4 * SZ;
    float* opart = (float*)(wsb + 5 * SZ);
    float* mpart = opart + (size_t)SPLIT * N_TOK * D_H;
    float* lpart = mpart + (size_t)SPLIT * N_TOK;

    qkv_kernel<<<dim3(N_TOK / QKV_BM, 3), 256, 0, stream>>>(x, Wq, Wk, Wv,
                                                            qh, ql, kh, kl, vt);
    flash_kernel<<<dim3(N_TOK / BQ, SPLIT), 256, 0, stream>>>(qh, ql, kh, kl, vt,
                                                              opart, mpart, lpart);
    combine_kernel<<<dim3(N_TOK / 16), 256, 0, stream>>>(opart, mpart, lpart, out);
}

// Round 4
// 366.693 us; speedup vs baseline: 3.8131x; 1.3981x over previous
//
#include <hip/hip_runtime.h>
#include <hip/hip_bf16.h>
#include <math.h>

#define N_TOK 8192
#define D_IN  1024
#define D_H   128
#define SPLIT 6

typedef __bf16 bf16;
typedef __attribute__((ext_vector_type(4))) __bf16 bf16x4;
typedef __attribute__((ext_vector_type(8))) __bf16 bf16x8;
typedef __attribute__((ext_vector_type(4))) float floatx4;

#define MFMA16(a, b, c) __builtin_amdgcn_mfma_f32_16x16x32_bf16((a), (b), (c), 0, 0, 0)

// ---------------------------------------------------------------------------
// Kernel 1: QKV projection via split-bf16 MFMA (3-pass), fp32 accumulate.
// grid (N/64, 3), block 256 = 4 waves in 2x2; wave computes 32x64 of the
// 64x128 tile. fp32 x/W are converted to (hi,lo) bf16 during LDS staging.
// Epilogue: y=0 -> qh/ql (scale sqrt(128) folded), y=1 -> kh/kl, y=2 -> vt^T.
// ---------------------------------------------------------------------------
#define PJ_BM 64
#define PJ_BK 64
#define PJ_LS 72    // 64+8 bf16: 144 B row stride, 16B-aligned, 2-way max

__global__ __launch_bounds__(256)
void qkv_kernel(const float* __restrict__ x,
                const float* __restrict__ Wq,
                const float* __restrict__ Wk,
                const float* __restrict__ Wv,
                bf16* __restrict__ q_hi, bf16* __restrict__ q_lo,
                bf16* __restrict__ k_hi, bf16* __restrict__ k_lo,
                bf16* __restrict__ vt)
{
    const float* W = (blockIdx.y == 0) ? Wq : (blockIdx.y == 1) ? Wk : Wv;

    __shared__ bf16 ah_s[PJ_BM][PJ_LS];
    __shared__ bf16 al_s[PJ_BM][PJ_LS];
    __shared__ bf16 bh_s[D_H][PJ_LS];
    __shared__ bf16 bl_s[D_H][PJ_LS];

    const int t    = threadIdx.x;
    const int lane = t & 63;
    const int wid  = t >> 6;
    const int wr   = wid >> 1;       // row half (0..1)
    const int wc   = wid & 1;        // col half (0..1)
    const int lid  = lane & 15;
    const int quad = lane >> 4;
    const int m0   = blockIdx.x * PJ_BM;

    floatx4 acc[2][4];
    #pragma unroll
    for (int s2 = 0; s2 < 2; ++s2)
        #pragma unroll
        for (int ct = 0; ct < 4; ++ct)
            #pragma unroll
            for (int r = 0; r < 4; ++r) acc[s2][ct][r] = 0.f;

    for (int k0 = 0; k0 < D_IN; k0 += PJ_BK) {
        __syncthreads();
        // stage x tile 64x64: 1024 float4, 4/thread; convert to split-bf16
        #pragma unroll
        for (int i = 0; i < 4; ++i) {
            int f  = t + i * 256;
            int r  = f >> 4;                 // 16 float4 per row
            int c4 = (f & 15) << 2;
            float4 xv = *(const float4*)&x[(size_t)(m0 + r) * D_IN + k0 + c4];
            bf16x4 h, l;
            float vv[4] = { xv.x, xv.y, xv.z, xv.w };
            #pragma unroll
            for (int j = 0; j < 4; ++j) {
                bf16 hh = (bf16)vv[j];
                h[j] = hh;
                l[j] = (bf16)(vv[j] - (float)hh);
            }
            *(bf16x4*)&ah_s[r][c4] = h;
            *(bf16x4*)&al_s[r][c4] = l;
        }
        // stage W tile 128x64: 2048 float4, 8/thread
        #pragma unroll
        for (int i = 0; i < 8; ++i) {
            int f  = t + i * 256;
            int r  = f >> 4;
            int c4 = (f & 15) << 2;
            float4 wv = *(const float4*)&W[(size_t)r * D_IN + k0 + c4];
            bf16x4 h, l;
            float vv[4] = { wv.x, wv.y, wv.z, wv.w };
            #pragma unroll
            for (int j = 0; j < 4; ++j) {
                bf16 hh = (bf16)vv[j];
                h[j] = hh;
                l[j] = (bf16)(vv[j] - (float)hh);
            }
            *(bf16x4*)&bh_s[r][c4] = h;
            *(bf16x4*)&bl_s[r][c4] = l;
        }
        __syncthreads();

        #pragma unroll
        for (int kc = 0; kc < 2; ++kc) {
            bf16x8 ah[2], al[2], bh[4], bl[4];
            #pragma unroll
            for (int s2 = 0; s2 < 2; ++s2) {
                ah[s2] = *(const bf16x8*)&ah_s[wr * 32 + s2 * 16 + lid][kc * 32 + quad * 8];
                al[s2] = *(const bf16x8*)&al_s[wr * 32 + s2 * 16 + lid][kc * 32 + quad * 8];
            }
            #pragma unroll
            for (int ct = 0; ct < 4; ++ct) {
                bh[ct] = *(const bf16x8*)&bh_s[wc * 64 + ct * 16 + lid][kc * 32 + quad * 8];
                bl[ct] = *(const bf16x8*)&bl_s[wc * 64 + ct * 16 + lid][kc * 32 + quad * 8];
            }
            #pragma unroll
            for (int s2 = 0; s2 < 2; ++s2)
                #pragma unroll
                for (int ct = 0; ct < 4; ++ct) {
                    acc[s2][ct] = MFMA16(ah[s2], bh[ct], acc[s2][ct]);
                    acc[s2][ct] = MFMA16(al[s2], bh[ct], acc[s2][ct]);
                    acc[s2][ct] = MFMA16(ah[s2], bl[ct], acc[s2][ct]);
                }
        }
    }

    // epilogue: C-layout col = ct*16+lid (within wave cols), row = quad*4+r
    if (blockIdx.y <= 1) {
        bf16* hi_out = (blockIdx.y == 0) ? q_hi : k_hi;
        bf16* lo_out = (blockIdx.y == 0) ? q_lo : k_lo;
        const float sc = (blockIdx.y == 0) ? 11.313708498984760390f : 1.0f;
        #pragma unroll
        for (int s2 = 0; s2 < 2; ++s2)
            #pragma unroll
            for (int ct = 0; ct < 4; ++ct)
                #pragma unroll
                for (int r = 0; r < 4; ++r) {
                    int row = m0 + wr * 32 + s2 * 16 + quad * 4 + r;
                    int col = wc * 64 + ct * 16 + lid;
                    float a = acc[s2][ct][r] * sc;
                    bf16 h = (bf16)a;
                    hi_out[(size_t)row * D_H + col] = h;
                    lo_out[(size_t)row * D_H + col] = (bf16)(a - (float)h);
                }
    } else {
        #pragma unroll
        for (int s2 = 0; s2 < 2; ++s2)
            #pragma unroll
            for (int ct = 0; ct < 4; ++ct)
                #pragma unroll
                for (int r = 0; r < 4; ++r) {
                    int row = m0 + wr * 32 + s2 * 16 + quad * 4 + r;
                    int col = wc * 64 + ct * 16 + lid;
                    vt[(size_t)col * N_TOK + row] = (bf16)acc[s2][ct][r];
                }
    }
}

// ---------------------------------------------------------------------------
// Kernel 2: flash attention, split-bf16 MFMA, key-split 6 ways.
// grid (N/64, 6) = 768 blocks = 3 blocks/CU (LDS 44 KB). V-fragments read
// directly from global vt (L2-hot, 2 MB); kc2=0 group preloaded before the
// softmax so its latency hides behind the serial shfl/exp chain.
// ---------------------------------------------------------------------------
#define BQ   64
#define BKEY 64
#define KLS  136
#define PLS  72

__global__ __launch_bounds__(256, 3)
void flash_kernel(const bf16* __restrict__ qh, const bf16* __restrict__ ql,
                  const bf16* __restrict__ kh, const bf16* __restrict__ kl,
                  const bf16* __restrict__ vt,
                  bf16*  __restrict__ opart,   // [SPLIT][N][D_H] unnormalized
                  float* __restrict__ mpart,   // [SPLIT][N]
                  float* __restrict__ lpart)   // [SPLIT][N]
{
    __shared__ bf16 kh_s[BKEY][KLS];
    __shared__ bf16 kl_s[BKEY][KLS];
    __shared__ bf16 p_s[BQ][PLS];

    const int t    = threadIdx.x;
    const int lane = t & 63;
    const int wid  = t >> 6;
    const int lid  = lane & 15;
    const int quad = lane >> 4;
    const int q0   = blockIdx.x * BQ;
    const int strip = wid * 16;
    const int sp    = blockIdx.y;
    const int base  = ((sp * 128) / SPLIT) * BKEY;       // balanced tile split
    const int end   = (((sp + 1) * 128) / SPLIT) * BKEY;

    bf16x8 a_hi[4], a_lo[4];
    {
        const size_t rowb = (size_t)(q0 + strip + lid) * D_H + quad * 8;
        #pragma unroll
        for (int kc = 0; kc < 4; ++kc) {
            a_hi[kc] = *(const bf16x8*)(qh + rowb + kc * 32);
            a_lo[kc] = *(const bf16x8*)(ql + rowb + kc * 32);
        }
    }

    float m_run[4] = { -INFINITY, -INFINITY, -INFINITY, -INFINITY };
    float l_run[4] = { 0.f, 0.f, 0.f, 0.f };
    floatx4 o_acc[8];
    #pragma unroll
    for (int ct = 0; ct < 8; ++ct)
        #pragma unroll
        for (int r = 0; r < 4; ++r) o_acc[ct][r] = 0.f;

    uint4 rkh[4], rkl[4];
    auto load_k = [&](int kt) {
        #pragma unroll
        for (int i = 0; i < 4; ++i) {
            int idx  = t + i * 256;
            int key  = idx >> 4, coff = (idx & 15) << 3;
            rkh[i] = *(const uint4*)(kh + (size_t)(kt + key) * D_H + coff);
            rkl[i] = *(const uint4*)(kl + (size_t)(kt + key) * D_H + coff);
        }
    };

    load_k(base);

    for (int kt = base; kt < end; kt += BKEY) {
        __syncthreads();
        #pragma unroll
        for (int i = 0; i < 4; ++i) {
            int idx  = t + i * 256;
            int key  = idx >> 4, coff = (idx & 15) << 3;
            *(uint4*)&kh_s[key][coff] = rkh[i];
            *(uint4*)&kl_s[key][coff] = rkl[i];
        }
        __syncthreads();
        if (kt + BKEY < end) load_k(kt + BKEY);

        // ---- S = (scaled q) . k^T, split-bf16 3-pass ----
        floatx4 s[4];
        #pragma unroll
        for (int ct = 0; ct < 4; ++ct)
            #pragma unroll
            for (int r = 0; r < 4; ++r) s[ct][r] = 0.f;

        #pragma unroll
        for (int kc = 0; kc < 4; ++kc) {
            #pragma unroll
            for (int ct = 0; ct < 4; ++ct) {
                bf16x8 bh = *(const bf16x8*)&kh_s[ct * 16 + lid][kc * 32 + quad * 8];
                bf16x8 bl = *(const bf16x8*)&kl_s[ct * 16 + lid][kc * 32 + quad * 8];
                s[ct] = MFMA16(a_hi[kc], bh, s[ct]);
                s[ct] = MFMA16(a_lo[kc], bh, s[ct]);
                s[ct] = MFMA16(a_hi[kc], bl, s[ct]);
            }
        }

        // ---- preload V-frags for kc2=0 (latency hides behind softmax) ----
        bf16x8 bv0[8];
        #pragma unroll
        for (int ct = 0; ct < 8; ++ct)
            bv0[ct] = *(const bf16x8*)(vt + (size_t)(ct * 16 + lid) * N_TOK
                                       + kt + quad * 8);

        // ---- online softmax (rows strip+quad*4+r, cols across 16 lanes) ----
        float alpha[4];
        #pragma unroll
        for (int r = 0; r < 4; ++r) {
            float m = fmaxf(fmaxf(s[0][r], s[1][r]), fmaxf(s[2][r], s[3][r]));
            #pragma unroll
            for (int off = 1; off < 16; off <<= 1)
                m = fmaxf(m, __shfl_xor(m, off, 64));
            float mn = fmaxf(m_run[r], m);
            alpha[r] = __expf(m_run[r] - mn);
            m_run[r] = mn;
            float rs = 0.f;
            float p[4];
            #pragma unroll
            for (int ct = 0; ct < 4; ++ct) {
                p[ct] = __expf(s[ct][r] - mn);
                rs += p[ct];
            }
            #pragma unroll
            for (int off = 1; off < 16; off <<= 1)
                rs += __shfl_xor(rs, off, 64);
            l_run[r] = l_run[r] * alpha[r] + rs;
            #pragma unroll
            for (int ct = 0; ct < 4; ++ct)
                p_s[strip + quad * 4 + r][ct * 16 + lid] = (bf16)p[ct];
        }

        #pragma unroll
        for (int ct = 0; ct < 8; ++ct)
            #pragma unroll
            for (int r = 0; r < 4; ++r)
                o_acc[ct][r] *= alpha[r];

        // ---- O += P V  (V direct from global) ----
        {
            bf16x8 ap0 = *(const bf16x8*)&p_s[strip + lid][quad * 8];
            bf16x8 bv1[8];
            #pragma unroll
            for (int ct = 0; ct < 8; ++ct)
                bv1[ct] = *(const bf16x8*)(vt + (size_t)(ct * 16 + lid) * N_TOK
                                           + kt + 32 + quad * 8);
            #pragma unroll
            for (int ct = 0; ct < 8; ++ct)
                o_acc[ct] = MFMA16(ap0, bv0[ct], o_acc[ct]);
            bf16x8 ap1 = *(const bf16x8*)&p_s[strip + lid][32 + quad * 8];
            #pragma unroll
            for (int ct = 0; ct < 8; ++ct)
                o_acc[ct] = MFMA16(ap1, bv1[ct], o_acc[ct]);
        }
    }

    // ---- epilogue: unnormalized partials (bf16) + row stats ----
    bf16* op = opart + (size_t)sp * N_TOK * D_H;
    #pragma unroll
    for (int ct = 0; ct < 8; ++ct)
        #pragma unroll
        for (int r = 0; r < 4; ++r)
            op[(size_t)(q0 + strip + quad * 4 + r) * D_H + ct * 16 + lid] =
                (bf16)o_acc[ct][r];
    if (lid == 0) {
        #pragma unroll
        for (int r = 0; r < 4; ++r) {
            int row = q0 + strip + quad * 4 + r;
            mpart[(size_t)sp * N_TOK + row] = m_run[r];
            lpart[(size_t)sp * N_TOK + row] = l_run[r];
        }
    }
}

// ---------------------------------------------------------------------------
// Kernel 3: merge the SPLIT partials.
// ---------------------------------------------------------------------------
__global__ __launch_bounds__(256)
void combine_kernel(const bf16* __restrict__ opart,
                    const float* __restrict__ mpart,
                    const float* __restrict__ lpart,
                    float* __restrict__ out)
{
    const int t   = threadIdx.x;
    const int row = blockIdx.x * 16 + (t >> 4);
    const int c0  = (t & 15) * 8;

    float ms[SPLIT], ls[SPLIT];
    float mstar = -INFINITY;
    #pragma unroll
    for (int s = 0; s < SPLIT; ++s) {
        ms[s] = mpart[(size_t)s * N_TOK + row];
        ls[s] = lpart[(size_t)s * N_TOK + row];
        mstar = fmaxf(mstar, ms[s]);
    }
    float acc[8] = {};
    float L = 0.f;
    #pragma unroll
    for (int s = 0; s < SPLIT; ++s) {
        float w = __expf(ms[s] - mstar);
        L += w * ls[s];
        bf16x8 o = *(const bf16x8*)&opart[((size_t)s * N_TOK + row) * D_H + c0];
        #pragma unroll
        for (int j = 0; j < 8; ++j)
            acc[j] += w * (float)o[j];
    }
    float inv = 1.f / L;
    float* dst = &out[(size_t)row * D_H + c0];
    *(float4*)(dst + 0) = make_float4(acc[0] * inv, acc[1] * inv,
                                      acc[2] * inv, acc[3] * inv);
    *(float4*)(dst + 4) = make_float4(acc[4] * inv, acc[5] * inv,
                                      acc[6] * inv, acc[7] * inv);
}

// ---------------------------------------------------------------------------
extern "C" void kernel_launch(void* const* d_in, const int* in_sizes, int n_in,
                              void* d_out, int out_size, void* d_ws, size_t ws_size,
                              hipStream_t stream) {
    const float* x  = (const float*)d_in[0];
    const float* Wq = (const float*)d_in[1];
    const float* Wk = (const float*)d_in[2];
    const float* Wv = (const float*)d_in[3];
    float* out = (float*)d_out;

    // ws layout (bf16): qh,ql,kh,kl [N][128], vt [128][N], opart [6][N][128]
    //                   then fp32 mpart/lpart [6][N].  Total ~23.5 MB.
    bf16* wsb = (bf16*)d_ws;
    const size_t SZ = (size_t)N_TOK * D_H;
    bf16* qh = wsb;
    bf16* ql = wsb + SZ;
    bf16* kh = wsb + 2 * SZ;
    bf16* kl = wsb + 3 * SZ;
    bf16* vt = wsb + 4 * SZ;
    bf16* opart = wsb + 5 * SZ;
    float* mpart = (float*)(wsb + (5 + SPLIT) * SZ);
    float* lpart = mpart + (size_t)SPLIT * N_TOK;

    qkv_kernel<<<dim3(N_TOK / PJ_BM, 3), 256, 0, stream>>>(x, Wq, Wk, Wv,
                                                           qh, ql, kh, kl, vt);
    flash_kernel<<<dim3(N_TOK / BQ, SPLIT), 256, 0, stream>>>(qh, ql, kh, kl, vt,
                                                              opart, mpart, lpart);
    combine_kernel<<<dim3(N_TOK / 16), 256, 0, stream>>>(opart, mpart, lpart, out);
}

// Round 5
// 300.773 us; speedup vs baseline: 4.6488x; 1.2192x over previous
//
#include <hip/hip_runtime.h>
#include <hip/hip_bf16.h>
#include <math.h>

#define N_TOK 8192
#define D_IN  1024
#define D_H   128
#define SPLIT 6

typedef __bf16 bf16;
typedef __attribute__((ext_vector_type(4))) __bf16 bf16x4;
typedef __attribute__((ext_vector_type(8))) __bf16 bf16x8;
typedef __attribute__((ext_vector_type(4))) float floatx4;

#define MFMA16(a, b, c) __builtin_amdgcn_mfma_f32_16x16x32_bf16((a), (b), (c), 0, 0, 0)

// vtf fragment-order index for V[n][d] (n = token, d = head dim):
//   tile = n>>6, ct = d>>4, lane = ((n>>3)&7)*16 + (d&15), j = n&7
//   flat = (tile*8 + ct)*1024 + lane*8 + j
__device__ __forceinline__ size_t vtf_idx(int n, int d) {
    return ((size_t)((n >> 6) * 8 + (d >> 4)) << 10)
         + (((n >> 3) & 7) << 7) + ((d & 15) << 3) + (n & 7);
}

// ---------------------------------------------------------------------------
// Kernel 1: QKV projection via split-bf16 MFMA (3-pass), fp32 accumulate.
// (structure unchanged from round 4; y==2 now emits V in vtf fragment order)
// ---------------------------------------------------------------------------
#define PJ_BM 64
#define PJ_BK 64
#define PJ_LS 72

__global__ __launch_bounds__(256)
void qkv_kernel(const float* __restrict__ x,
                const float* __restrict__ Wq,
                const float* __restrict__ Wk,
                const float* __restrict__ Wv,
                bf16* __restrict__ q_hi, bf16* __restrict__ q_lo,
                bf16* __restrict__ k_hi, bf16* __restrict__ k_lo,
                bf16* __restrict__ vtf)
{
    const float* W = (blockIdx.y == 0) ? Wq : (blockIdx.y == 1) ? Wk : Wv;

    __shared__ bf16 ah_s[PJ_BM][PJ_LS];
    __shared__ bf16 al_s[PJ_BM][PJ_LS];
    __shared__ bf16 bh_s[D_H][PJ_LS];
    __shared__ bf16 bl_s[D_H][PJ_LS];

    const int t    = threadIdx.x;
    const int lane = t & 63;
    const int wid  = t >> 6;
    const int wr   = wid >> 1;
    const int wc   = wid & 1;
    const int lid  = lane & 15;
    const int quad = lane >> 4;
    const int m0   = blockIdx.x * PJ_BM;

    floatx4 acc[2][4];
    #pragma unroll
    for (int s2 = 0; s2 < 2; ++s2)
        #pragma unroll
        for (int ct = 0; ct < 4; ++ct)
            #pragma unroll
            for (int r = 0; r < 4; ++r) acc[s2][ct][r] = 0.f;

    for (int k0 = 0; k0 < D_IN; k0 += PJ_BK) {
        __syncthreads();
        #pragma unroll
        for (int i = 0; i < 4; ++i) {
            int f  = t + i * 256;
            int r  = f >> 4;
            int c4 = (f & 15) << 2;
            float4 xv = *(const float4*)&x[(size_t)(m0 + r) * D_IN + k0 + c4];
            bf16x4 h, l;
            float vv[4] = { xv.x, xv.y, xv.z, xv.w };
            #pragma unroll
            for (int j = 0; j < 4; ++j) {
                bf16 hh = (bf16)vv[j];
                h[j] = hh;
                l[j] = (bf16)(vv[j] - (float)hh);
            }
            *(bf16x4*)&ah_s[r][c4] = h;
            *(bf16x4*)&al_s[r][c4] = l;
        }
        #pragma unroll
        for (int i = 0; i < 8; ++i) {
            int f  = t + i * 256;
            int r  = f >> 4;
            int c4 = (f & 15) << 2;
            float4 wv = *(const float4*)&W[(size_t)r * D_IN + k0 + c4];
            bf16x4 h, l;
            float vv[4] = { wv.x, wv.y, wv.z, wv.w };
            #pragma unroll
            for (int j = 0; j < 4; ++j) {
                bf16 hh = (bf16)vv[j];
                h[j] = hh;
                l[j] = (bf16)(vv[j] - (float)hh);
            }
            *(bf16x4*)&bh_s[r][c4] = h;
            *(bf16x4*)&bl_s[r][c4] = l;
        }
        __syncthreads();

        #pragma unroll
        for (int kc = 0; kc < 2; ++kc) {
            bf16x8 ah[2], al[2], bh[4], bl[4];
            #pragma unroll
            for (int s2 = 0; s2 < 2; ++s2) {
                ah[s2] = *(const bf16x8*)&ah_s[wr * 32 + s2 * 16 + lid][kc * 32 + quad * 8];
                al[s2] = *(const bf16x8*)&al_s[wr * 32 + s2 * 16 + lid][kc * 32 + quad * 8];
            }
            #pragma unroll
            for (int ct = 0; ct < 4; ++ct) {
                bh[ct] = *(const bf16x8*)&bh_s[wc * 64 + ct * 16 + lid][kc * 32 + quad * 8];
                bl[ct] = *(const bf16x8*)&bl_s[wc * 64 + ct * 16 + lid][kc * 32 + quad * 8];
            }
            #pragma unroll
            for (int s2 = 0; s2 < 2; ++s2)
                #pragma unroll
                for (int ct = 0; ct < 4; ++ct) {
                    acc[s2][ct] = MFMA16(ah[s2], bh[ct], acc[s2][ct]);
                    acc[s2][ct] = MFMA16(al[s2], bh[ct], acc[s2][ct]);
                    acc[s2][ct] = MFMA16(ah[s2], bl[ct], acc[s2][ct]);
                }
        }
    }

    if (blockIdx.y <= 1) {
        bf16* hi_out = (blockIdx.y == 0) ? q_hi : k_hi;
        bf16* lo_out = (blockIdx.y == 0) ? q_lo : k_lo;
        const float sc = (blockIdx.y == 0) ? 11.313708498984760390f : 1.0f;
        #pragma unroll
        for (int s2 = 0; s2 < 2; ++s2)
            #pragma unroll
            for (int ct = 0; ct < 4; ++ct)
                #pragma unroll
                for (int r = 0; r < 4; ++r) {
                    int row = m0 + wr * 32 + s2 * 16 + quad * 4 + r;
                    int col = wc * 64 + ct * 16 + lid;
                    float a = acc[s2][ct][r] * sc;
                    bf16 h = (bf16)a;
                    hi_out[(size_t)row * D_H + col] = h;
                    lo_out[(size_t)row * D_H + col] = (bf16)(a - (float)h);
                }
    } else {
        // V in fragment order (scattered 2B writes, 2 MB once — cheap)
        #pragma unroll
        for (int s2 = 0; s2 < 2; ++s2)
            #pragma unroll
            for (int ct = 0; ct < 4; ++ct)
                #pragma unroll
                for (int r = 0; r < 4; ++r) {
                    int n = m0 + wr * 32 + s2 * 16 + quad * 4 + r;
                    int d = wc * 64 + ct * 16 + lid;
                    vtf[vtf_idx(n, d)] = (bf16)acc[s2][ct][r];
                }
    }
}

// ---------------------------------------------------------------------------
// Kernel 2: flash attention, split-bf16 MFMA, key-split 6 ways.
// grid (N/64, 6) = 768 blocks = 3 blocks/CU (LDS 44 KB, VGPR <= 170).
// V read direct from global in COALESCED fragment order (vtf); both kc2
// fragment groups prefetched before the softmax chain. Row-sum l computed
// by MFMA against an all-ones B fragment (no sum-shfl chain).
// ---------------------------------------------------------------------------
#define BQ   64
#define BKEY 64
#define KLS  136
#define PLS  72

__global__ __launch_bounds__(256, 3)
void flash_kernel(const bf16* __restrict__ qh, const bf16* __restrict__ ql,
                  const bf16* __restrict__ kh, const bf16* __restrict__ kl,
                  const bf16* __restrict__ vtf,
                  bf16*  __restrict__ opart,   // [SPLIT][N][D_H] unnormalized
                  float* __restrict__ mpart,   // [SPLIT][N]
                  float* __restrict__ lpart)   // [SPLIT][N]
{
    __shared__ bf16 kh_s[BKEY][KLS];
    __shared__ bf16 kl_s[BKEY][KLS];
    __shared__ bf16 p_s[BQ][PLS];

    const int t    = threadIdx.x;
    const int lane = t & 63;
    const int wid  = t >> 6;
    const int lid  = lane & 15;
    const int quad = lane >> 4;
    const int q0   = blockIdx.x * BQ;
    const int strip = wid * 16;
    const int sp    = blockIdx.y;
    const int base  = ((sp * 128) / SPLIT) * BKEY;
    const int end   = (((sp + 1) * 128) / SPLIT) * BKEY;

    bf16x8 a_hi[4], a_lo[4];
    {
        const size_t rowb = (size_t)(q0 + strip + lid) * D_H + quad * 8;
        #pragma unroll
        for (int kc = 0; kc < 4; ++kc) {
            a_hi[kc] = *(const bf16x8*)(qh + rowb + kc * 32);
            a_lo[kc] = *(const bf16x8*)(ql + rowb + kc * 32);
        }
    }

    bf16x8 vones;
    #pragma unroll
    for (int j = 0; j < 8; ++j) vones[j] = (bf16)1.0f;

    float m_run[4] = { -INFINITY, -INFINITY, -INFINITY, -INFINITY };
    floatx4 l_acc;
    #pragma unroll
    for (int r = 0; r < 4; ++r) l_acc[r] = 0.f;
    floatx4 o_acc[8];
    #pragma unroll
    for (int ct = 0; ct < 8; ++ct)
        #pragma unroll
        for (int r = 0; r < 4; ++r) o_acc[ct][r] = 0.f;

    uint4 rkh[4], rkl[4];
    auto load_k = [&](int kt) {
        #pragma unroll
        for (int i = 0; i < 4; ++i) {
            int idx  = t + i * 256;
            int key  = idx >> 4, coff = (idx & 15) << 3;
            rkh[i] = *(const uint4*)(kh + (size_t)(kt + key) * D_H + coff);
            rkl[i] = *(const uint4*)(kl + (size_t)(kt + key) * D_H + coff);
        }
    };

    load_k(base);

    for (int kt = base; kt < end; kt += BKEY) {
        __syncthreads();
        #pragma unroll
        for (int i = 0; i < 4; ++i) {
            int idx  = t + i * 256;
            int key  = idx >> 4, coff = (idx & 15) << 3;
            *(uint4*)&kh_s[key][coff] = rkh[i];
            *(uint4*)&kl_s[key][coff] = rkl[i];
        }
        __syncthreads();
        if (kt + BKEY < end) load_k(kt + BKEY);

        // ---- S = (scaled q) . k^T, split-bf16 3-pass ----
        floatx4 s[4];
        #pragma unroll
        for (int ct = 0; ct < 4; ++ct)
            #pragma unroll
            for (int r = 0; r < 4; ++r) s[ct][r] = 0.f;

        #pragma unroll
        for (int kc = 0; kc < 4; ++kc) {
            #pragma unroll
            for (int ct = 0; ct < 4; ++ct) {
                bf16x8 bh = *(const bf16x8*)&kh_s[ct * 16 + lid][kc * 32 + quad * 8];
                bf16x8 bl = *(const bf16x8*)&kl_s[ct * 16 + lid][kc * 32 + quad * 8];
                s[ct] = MFMA16(a_hi[kc], bh, s[ct]);
                s[ct] = MFMA16(a_lo[kc], bh, s[ct]);
                s[ct] = MFMA16(a_hi[kc], bl, s[ct]);
            }
        }

        // ---- prefetch BOTH V fragment groups (coalesced; hides under softmax)
        bf16x8 bv0[8], bv1[8];
        {
            const bf16* vb = vtf + (((size_t)(kt >> 6) * 8) << 10) + (lane << 3);
            #pragma unroll
            for (int ct = 0; ct < 8; ++ct) {
                bv0[ct] = *(const bf16x8*)(vb + ((size_t)ct << 10));
                bv1[ct] = *(const bf16x8*)(vb + ((size_t)ct << 10) + 512);
            }
        }

        // ---- online softmax: max via 4-step DPP shfl; sum via ones-MFMA ----
        float alpha[4];
        #pragma unroll
        for (int r = 0; r < 4; ++r) {
            float m = fmaxf(fmaxf(s[0][r], s[1][r]), fmaxf(s[2][r], s[3][r]));
            #pragma unroll
            for (int off = 1; off < 16; off <<= 1)
                m = fmaxf(m, __shfl_xor(m, off, 64));
            float mn = fmaxf(m_run[r], m);
            alpha[r] = __expf(m_run[r] - mn);
            m_run[r] = mn;
            #pragma unroll
            for (int ct = 0; ct < 4; ++ct)
                p_s[strip + quad * 4 + r][ct * 16 + lid] =
                    (bf16)__expf(s[ct][r] - mn);
        }

        #pragma unroll
        for (int r = 0; r < 4; ++r) l_acc[r] *= alpha[r];
        #pragma unroll
        for (int ct = 0; ct < 8; ++ct)
            #pragma unroll
            for (int r = 0; r < 4; ++r)
                o_acc[ct][r] *= alpha[r];

        // ---- O += P V ; l += P . 1 ----
        {
            bf16x8 ap0 = *(const bf16x8*)&p_s[strip + lid][quad * 8];
            l_acc = MFMA16(ap0, vones, l_acc);
            #pragma unroll
            for (int ct = 0; ct < 8; ++ct)
                o_acc[ct] = MFMA16(ap0, bv0[ct], o_acc[ct]);
            bf16x8 ap1 = *(const bf16x8*)&p_s[strip + lid][32 + quad * 8];
            l_acc = MFMA16(ap1, vones, l_acc);
            #pragma unroll
            for (int ct = 0; ct < 8; ++ct)
                o_acc[ct] = MFMA16(ap1, bv1[ct], o_acc[ct]);
        }
    }

    // ---- epilogue: unnormalized partials (bf16) + row stats ----
    bf16* op = opart + (size_t)sp * N_TOK * D_H;
    #pragma unroll
    for (int ct = 0; ct < 8; ++ct)
        #pragma unroll
        for (int r = 0; r < 4; ++r)
            op[(size_t)(q0 + strip + quad * 4 + r) * D_H + ct * 16 + lid] =
                (bf16)o_acc[ct][r];
    if (lid == 0) {
        #pragma unroll
        for (int r = 0; r < 4; ++r) {
            int row = q0 + strip + quad * 4 + r;
            mpart[(size_t)sp * N_TOK + row] = m_run[r];
            lpart[(size_t)sp * N_TOK + row] = l_acc[r];
        }
    }
}

// ---------------------------------------------------------------------------
// Kernel 3: merge the SPLIT partials.
// ---------------------------------------------------------------------------
__global__ __launch_bounds__(256)
void combine_kernel(const bf16* __restrict__ opart,
                    const float* __restrict__ mpart,
                    const float* __restrict__ lpart,
                    float* __restrict__ out)
{
    const int t   = threadIdx.x;
    const int row = blockIdx.x * 16 + (t >> 4);
    const int c0  = (t & 15) * 8;

    float ms[SPLIT], ls[SPLIT];
    float mstar = -INFINITY;
    #pragma unroll
    for (int s = 0; s < SPLIT; ++s) {
        ms[s] = mpart[(size_t)s * N_TOK + row];
        ls[s] = lpart[(size_t)s * N_TOK + row];
        mstar = fmaxf(mstar, ms[s]);
    }
    float acc[8] = {};
    float L = 0.f;
    #pragma unroll
    for (int s = 0; s < SPLIT; ++s) {
        float w = __expf(ms[s] - mstar);
        L += w * ls[s];
        bf16x8 o = *(const bf16x8*)&opart[((size_t)s * N_TOK + row) * D_H + c0];
        #pragma unroll
        for (int j = 0; j < 8; ++j)
            acc[j] += w * (float)o[j];
    }
    float inv = 1.f / L;
    float* dst = &out[(size_t)row * D_H + c0];
    *(float4*)(dst + 0) = make_float4(acc[0] * inv, acc[1] * inv,
                                      acc[2] * inv, acc[3] * inv);
    *(float4*)(dst + 4) = make_float4(acc[4] * inv, acc[5] * inv,
                                      acc[6] * inv, acc[7] * inv);
}

// ---------------------------------------------------------------------------
extern "C" void kernel_launch(void* const* d_in, const int* in_sizes, int n_in,
                              void* d_out, int out_size, void* d_ws, size_t ws_size,
                              hipStream_t stream) {
    const float* x  = (const float*)d_in[0];
    const float* Wq = (const float*)d_in[1];
    const float* Wk = (const float*)d_in[2];
    const float* Wv = (const float*)d_in[3];
    float* out = (float*)d_out;

    // ws layout (bf16): qh,ql,kh,kl [N][128], vtf (fragment order, N*128),
    //                   opart [6][N][128]; then fp32 mpart/lpart [6][N].
    bf16* wsb = (bf16*)d_ws;
    const size_t SZ = (size_t)N_TOK * D_H;
    bf16* qh = wsb;
    bf16* ql = wsb + SZ;
    bf16* kh = wsb + 2 * SZ;
    bf16* kl = wsb + 3 * SZ;
    bf16* vtf = wsb + 4 * SZ;
    bf16* opart = wsb + 5 * SZ;
    float* mpart = (float*)(wsb + (5 + SPLIT) * SZ);
    float* lpart = mpart + (size_t)SPLIT * N_TOK;

    qkv_kernel<<<dim3(N_TOK / PJ_BM, 3), 256, 0, stream>>>(x, Wq, Wk, Wv,
                                                           qh, ql, kh, kl, vtf);
    flash_kernel<<<dim3(N_TOK / BQ, SPLIT), 256, 0, stream>>>(qh, ql, kh, kl, vtf,
                                                              opart, mpart, lpart);
    combine_kernel<<<dim3(N_TOK / 16), 256, 0, stream>>>(opart, mpart, lpart, out);
}

// Round 6
// 196.788 us; speedup vs baseline: 7.1053x; 1.5284x over previous
//
#include <hip/hip_runtime.h>
#include <hip/hip_bf16.h>
#include <math.h>

#define N_TOK 8192
#define D_IN  1024
#define D_H   128
#define SPLIT 8

typedef __bf16 bf16;
typedef __attribute__((ext_vector_type(4))) __bf16 bf16x4;
typedef __attribute__((ext_vector_type(8))) __bf16 bf16x8;
typedef __attribute__((ext_vector_type(4))) float floatx4;

#define MFMA16(a, b, c) __builtin_amdgcn_mfma_f32_16x16x32_bf16((a), (b), (c), 0, 0, 0)

// V fragment order (B-operand for PV): [ntile][ct][lane][j]
__device__ __forceinline__ size_t vtf_idx(int n, int d) {
    return ((size_t)((n >> 6) * 8 + (d >> 4)) << 10)
         + (((n >> 3) & 7) << 7) + ((d & 15) << 3) + (n & 7);
}
// K fragment order (B-operand for QK^T): [ktile][kc][ct][lane][j]
//   key = ct*16 + (lane&15), d = kc*32 + (lane>>4)*8 + j
__device__ __forceinline__ size_t khf_idx(int n, int d) {
    return ((size_t)(((n >> 6) * 4 + (d >> 5)) * 4 + ((n >> 4) & 3)) << 9)
         + (((d >> 3) & 3) << 7) + ((n & 15) << 3) + (d & 7);
}

// ---------------------------------------------------------------------------
// Kernel 1: QKV projection via split-bf16 MFMA (3-pass), fp32 accumulate.
// y==0 -> qh/ql row-major (sqrt(128) folded); y==1 -> khf/klf fragment order;
// y==2 -> vtf fragment order.
// ---------------------------------------------------------------------------
#define PJ_BM 64
#define PJ_BK 64
#define PJ_LS 72

__global__ __launch_bounds__(256)
void qkv_kernel(const float* __restrict__ x,
                const float* __restrict__ Wq,
                const float* __restrict__ Wk,
                const float* __restrict__ Wv,
                bf16* __restrict__ q_hi, bf16* __restrict__ q_lo,
                bf16* __restrict__ khf, bf16* __restrict__ klf,
                bf16* __restrict__ vtf)
{
    const float* W = (blockIdx.y == 0) ? Wq : (blockIdx.y == 1) ? Wk : Wv;

    __shared__ bf16 ah_s[PJ_BM][PJ_LS];
    __shared__ bf16 al_s[PJ_BM][PJ_LS];
    __shared__ bf16 bh_s[D_H][PJ_LS];
    __shared__ bf16 bl_s[D_H][PJ_LS];

    const int t    = threadIdx.x;
    const int lane = t & 63;
    const int wid  = t >> 6;
    const int wr   = wid >> 1;
    const int wc   = wid & 1;
    const int lid  = lane & 15;
    const int quad = lane >> 4;
    const int m0   = blockIdx.x * PJ_BM;

    floatx4 acc[2][4];
    #pragma unroll
    for (int s2 = 0; s2 < 2; ++s2)
        #pragma unroll
        for (int ct = 0; ct < 4; ++ct)
            #pragma unroll
            for (int r = 0; r < 4; ++r) acc[s2][ct][r] = 0.f;

    for (int k0 = 0; k0 < D_IN; k0 += PJ_BK) {
        __syncthreads();
        #pragma unroll
        for (int i = 0; i < 4; ++i) {
            int f  = t + i * 256;
            int r  = f >> 4;
            int c4 = (f & 15) << 2;
            float4 xv = *(const float4*)&x[(size_t)(m0 + r) * D_IN + k0 + c4];
            bf16x4 h, l;
            float vv[4] = { xv.x, xv.y, xv.z, xv.w };
            #pragma unroll
            for (int j = 0; j < 4; ++j) {
                bf16 hh = (bf16)vv[j];
                h[j] = hh;
                l[j] = (bf16)(vv[j] - (float)hh);
            }
            *(bf16x4*)&ah_s[r][c4] = h;
            *(bf16x4*)&al_s[r][c4] = l;
        }
        #pragma unroll
        for (int i = 0; i < 8; ++i) {
            int f  = t + i * 256;
            int r  = f >> 4;
            int c4 = (f & 15) << 2;
            float4 wv = *(const float4*)&W[(size_t)r * D_IN + k0 + c4];
            bf16x4 h, l;
            float vv[4] = { wv.x, wv.y, wv.z, wv.w };
            #pragma unroll
            for (int j = 0; j < 4; ++j) {
                bf16 hh = (bf16)vv[j];
                h[j] = hh;
                l[j] = (bf16)(vv[j] - (float)hh);
            }
            *(bf16x4*)&bh_s[r][c4] = h;
            *(bf16x4*)&bl_s[r][c4] = l;
        }
        __syncthreads();

        #pragma unroll
        for (int kc = 0; kc < 2; ++kc) {
            bf16x8 ah[2], al[2], bh[4], bl[4];
            #pragma unroll
            for (int s2 = 0; s2 < 2; ++s2) {
                ah[s2] = *(const bf16x8*)&ah_s[wr * 32 + s2 * 16 + lid][kc * 32 + quad * 8];
                al[s2] = *(const bf16x8*)&al_s[wr * 32 + s2 * 16 + lid][kc * 32 + quad * 8];
            }
            #pragma unroll
            for (int ct = 0; ct < 4; ++ct) {
                bh[ct] = *(const bf16x8*)&bh_s[wc * 64 + ct * 16 + lid][kc * 32 + quad * 8];
                bl[ct] = *(const bf16x8*)&bl_s[wc * 64 + ct * 16 + lid][kc * 32 + quad * 8];
            }
            #pragma unroll
            for (int s2 = 0; s2 < 2; ++s2)
                #pragma unroll
                for (int ct = 0; ct < 4; ++ct) {
                    acc[s2][ct] = MFMA16(ah[s2], bh[ct], acc[s2][ct]);
                    acc[s2][ct] = MFMA16(al[s2], bh[ct], acc[s2][ct]);
                    acc[s2][ct] = MFMA16(ah[s2], bl[ct], acc[s2][ct]);
                }
        }
    }

    if (blockIdx.y == 0) {
        const float sc = 11.313708498984760390f;
        #pragma unroll
        for (int s2 = 0; s2 < 2; ++s2)
            #pragma unroll
            for (int ct = 0; ct < 4; ++ct)
                #pragma unroll
                for (int r = 0; r < 4; ++r) {
                    int row = m0 + wr * 32 + s2 * 16 + quad * 4 + r;
                    int col = wc * 64 + ct * 16 + lid;
                    float a = acc[s2][ct][r] * sc;
                    bf16 h = (bf16)a;
                    q_hi[(size_t)row * D_H + col] = h;
                    q_lo[(size_t)row * D_H + col] = (bf16)(a - (float)h);
                }
    } else if (blockIdx.y == 1) {
        #pragma unroll
        for (int s2 = 0; s2 < 2; ++s2)
            #pragma unroll
            for (int ct = 0; ct < 4; ++ct)
                #pragma unroll
                for (int r = 0; r < 4; ++r) {
                    int n = m0 + wr * 32 + s2 * 16 + quad * 4 + r;
                    int d = wc * 64 + ct * 16 + lid;
                    float a = acc[s2][ct][r];
                    bf16 h = (bf16)a;
                    size_t idx = khf_idx(n, d);
                    khf[idx] = h;
                    klf[idx] = (bf16)(a - (float)h);
                }
    } else {
        #pragma unroll
        for (int s2 = 0; s2 < 2; ++s2)
            #pragma unroll
            for (int ct = 0; ct < 4; ++ct)
                #pragma unroll
                for (int r = 0; r < 4; ++r) {
                    int n = m0 + wr * 32 + s2 * 16 + quad * 4 + r;
                    int d = wc * 64 + ct * 16 + lid;
                    vtf[vtf_idx(n, d)] = (bf16)acc[s2][ct][r];
                }
    }
}

// ---------------------------------------------------------------------------
// Kernel 2: flash attention. BQ=128/block (4 waves x 32 q-rows), BKEY=64,
// SPLIT=8 -> grid (64,8)=512 = 2 blocks/CU. K staged to LDS via async
// global_load_lds (fragment order, conflict-free b128 reads, no staging
// VGPRs). V direct from global in fragment order. P through LDS in
// A-fragment order. l via ones-MFMA. __launch_bounds__(256,2).
// ---------------------------------------------------------------------------
#define BQ   128
#define BKEY 64

__global__ __launch_bounds__(256, 2)
void flash_kernel(const bf16* __restrict__ qh, const bf16* __restrict__ ql,
                  const bf16* __restrict__ khf, const bf16* __restrict__ klf,
                  const bf16* __restrict__ vtf,
                  bf16*  __restrict__ opart,   // [SPLIT][N][D_H] unnormalized
                  float* __restrict__ mpart,   // [SPLIT][N]
                  float* __restrict__ lpart)   // [SPLIT][N]
{
    __shared__ bf16 kh_s[BKEY * D_H];     // fragment order, 16 KB
    __shared__ bf16 kl_s[BKEY * D_H];     // 16 KB
    __shared__ bf16 p_s[4 * 2048];        // per-wave A-frag P, 16 KB

    const int t     = threadIdx.x;
    const int lane  = t & 63;
    const int wid   = t >> 6;
    const int lid   = lane & 15;
    const int quad  = lane >> 4;
    const int q0    = blockIdx.x * BQ;
    const int strip = wid * 32;
    const int sp    = blockIdx.y;
    const int tile0 = sp * (N_TOK / BKEY / SPLIT);      // 16 tiles per split
    const int tile1 = tile0 + (N_TOK / BKEY / SPLIT);

    // ---- Q A-fragments: rows q0+strip+m*16+lid, resident all loop ----
    bf16x8 a_hi[2][4], a_lo[2][4];
    #pragma unroll
    for (int m = 0; m < 2; ++m) {
        const size_t rowb = (size_t)(q0 + strip + m * 16 + lid) * D_H + quad * 8;
        #pragma unroll
        for (int kc = 0; kc < 4; ++kc) {
            a_hi[m][kc] = *(const bf16x8*)(qh + rowb + kc * 32);
            a_lo[m][kc] = *(const bf16x8*)(ql + rowb + kc * 32);
        }
    }

    bf16x8 vones;
    #pragma unroll
    for (int j = 0; j < 8; ++j) vones[j] = (bf16)1.0f;

    float m_run[2][4];
    #pragma unroll
    for (int m = 0; m < 2; ++m)
        #pragma unroll
        for (int r = 0; r < 4; ++r) m_run[m][r] = -INFINITY;
    floatx4 l_acc[2];
    #pragma unroll
    for (int m = 0; m < 2; ++m)
        #pragma unroll
        for (int r = 0; r < 4; ++r) l_acc[m][r] = 0.f;
    floatx4 o_acc[2][8];
    #pragma unroll
    for (int m = 0; m < 2; ++m)
        #pragma unroll
        for (int ct = 0; ct < 8; ++ct)
            #pragma unroll
            for (int r = 0; r < 4; ++r) o_acc[m][ct][r] = 0.f;

    // async stage of one K tile (kh+kl, 32 KB) — wave w covers its quarter
    auto stage = [&](int tile) {
        const bf16* gh = khf + ((size_t)tile << 13) + (wid << 11) + (lane << 3);
        const bf16* gl = klf + ((size_t)tile << 13) + (wid << 11) + (lane << 3);
        bf16* lh = kh_s + (wid << 11);
        bf16* ll = kl_s + (wid << 11);
        #pragma unroll
        for (int i = 0; i < 4; ++i) {
            __builtin_amdgcn_global_load_lds(
                (const __attribute__((address_space(1))) void*)(gh + i * 512),
                (__attribute__((address_space(3))) void*)(lh + i * 512), 16, 0, 0);
            __builtin_amdgcn_global_load_lds(
                (const __attribute__((address_space(1))) void*)(gl + i * 512),
                (__attribute__((address_space(3))) void*)(ll + i * 512), 16, 0, 0);
        }
    };

    stage(tile0);

    for (int tt = tile0; tt < tile1; ++tt) {
        __syncthreads();     // K tile staged (vmcnt drained per-wave pre-barrier)

        // ---- S = (scaled q) . k^T : 3-pass split-bf16, 96 MFMA ----
        floatx4 s[2][4];
        #pragma unroll
        for (int m = 0; m < 2; ++m)
            #pragma unroll
            for (int ct = 0; ct < 4; ++ct)
                #pragma unroll
                for (int r = 0; r < 4; ++r) s[m][ct][r] = 0.f;

        #pragma unroll
        for (int kc = 0; kc < 4; ++kc)
            #pragma unroll
            for (int ct = 0; ct < 4; ++ct) {
                const int fo = ((kc * 4 + ct) << 9) + (lane << 3);
                bf16x8 bh = *(const bf16x8*)&kh_s[fo];
                bf16x8 bl = *(const bf16x8*)&kl_s[fo];
                #pragma unroll
                for (int m = 0; m < 2; ++m) {
                    s[m][ct] = MFMA16(a_hi[m][kc], bh, s[m][ct]);
                    s[m][ct] = MFMA16(a_lo[m][kc], bh, s[m][ct]);
                    s[m][ct] = MFMA16(a_hi[m][kc], bl, s[m][ct]);
                }
            }

        __syncthreads();     // all waves done reading K LDS
        if (tt + 1 < tile1) stage(tt + 1);   // overlaps softmax + PV

        // ---- prefetch V kc2=0 fragments (hide under softmax) ----
        const bf16* vb = vtf + (((size_t)tt * 8) << 10) + (lane << 3);
        bf16x8 bv0[8];
        #pragma unroll
        for (int ct = 0; ct < 8; ++ct)
            bv0[ct] = *(const bf16x8*)(vb + ((size_t)ct << 10));

        // ---- online softmax; P -> LDS in A-fragment order ----
        float alpha[2][4];
        #pragma unroll
        for (int m = 0; m < 2; ++m)
            #pragma unroll
            for (int r = 0; r < 4; ++r) {
                float mx = fmaxf(fmaxf(s[m][0][r], s[m][1][r]),
                                 fmaxf(s[m][2][r], s[m][3][r]));
                #pragma unroll
                for (int off = 1; off < 16; off <<= 1)
                    mx = fmaxf(mx, __shfl_xor(mx, off, 64));
                float mn = fmaxf(m_run[m][r], mx);
                alpha[m][r] = __expf(m_run[m][r] - mn);
                m_run[m][r] = mn;
                #pragma unroll
                for (int ct = 0; ct < 4; ++ct) {
                    float p = __expf(s[m][ct][r] - mn);
                    // A-frag slot: [m][kc2=ct>>1][lane'][j]
                    int fl = (((m * 2 + (ct >> 1)) << 6)
                              + (((ct & 1) * 2 + (lid >> 3)) << 4)
                              + quad * 4 + r) * 8 + (lid & 7);
                    p_s[(wid << 11) + fl] = (bf16)p;
                }
            }

        // ---- rescale O,l (skip when all alphas are 1) ----
        bool need = false;
        #pragma unroll
        for (int m = 0; m < 2; ++m)
            #pragma unroll
            for (int r = 0; r < 4; ++r) need |= (alpha[m][r] != 1.0f);
        if (__any(need)) {
            #pragma unroll
            for (int m = 0; m < 2; ++m) {
                #pragma unroll
                for (int r = 0; r < 4; ++r) l_acc[m][r] *= alpha[m][r];
                #pragma unroll
                for (int ct = 0; ct < 8; ++ct)
                    #pragma unroll
                    for (int r = 0; r < 4; ++r)
                        o_acc[m][ct][r] *= alpha[m][r];
            }
        }

        // ---- O += P V ; l += P . 1 ----
        {
            bf16x8 ap0[2];
            #pragma unroll
            for (int m = 0; m < 2; ++m)
                ap0[m] = *(const bf16x8*)&p_s[(wid << 11) + (((m * 2 + 0) << 6) << 3)
                                              + (lane << 3)];
            #pragma unroll
            for (int m = 0; m < 2; ++m)
                l_acc[m] = MFMA16(ap0[m], vones, l_acc[m]);
            #pragma unroll
            for (int ct = 0; ct < 8; ++ct)
                #pragma unroll
                for (int m = 0; m < 2; ++m)
                    o_acc[m][ct] = MFMA16(ap0[m], bv0[ct], o_acc[m][ct]);

            bf16x8 bv1[8];
            #pragma unroll
            for (int ct = 0; ct < 8; ++ct)
                bv1[ct] = *(const bf16x8*)(vb + ((size_t)ct << 10) + 512);
            bf16x8 ap1[2];
            #pragma unroll
            for (int m = 0; m < 2; ++m)
                ap1[m] = *(const bf16x8*)&p_s[(wid << 11) + (((m * 2 + 1) << 6) << 3)
                                              + (lane << 3)];
            #pragma unroll
            for (int m = 0; m < 2; ++m)
                l_acc[m] = MFMA16(ap1[m], vones, l_acc[m]);
            #pragma unroll
            for (int ct = 0; ct < 8; ++ct)
                #pragma unroll
                for (int m = 0; m < 2; ++m)
                    o_acc[m][ct] = MFMA16(ap1[m], bv1[ct], o_acc[m][ct]);
        }
    }

    // ---- epilogue: unnormalized partials (bf16) + row stats ----
    bf16* op = opart + (size_t)sp * N_TOK * D_H;
    #pragma unroll
    for (int m = 0; m < 2; ++m)
        #pragma unroll
        for (int ct = 0; ct < 8; ++ct)
            #pragma unroll
            for (int r = 0; r < 4; ++r)
                op[(size_t)(q0 + strip + m * 16 + quad * 4 + r) * D_H
                   + ct * 16 + lid] = (bf16)o_acc[m][ct][r];
    if (lid == 0) {
        #pragma unroll
        for (int m = 0; m < 2; ++m)
            #pragma unroll
            for (int r = 0; r < 4; ++r) {
                int row = q0 + strip + m * 16 + quad * 4 + r;
                mpart[(size_t)sp * N_TOK + row] = m_run[m][r];
                lpart[(size_t)sp * N_TOK + row] = l_acc[m][r];
            }
    }
}

// ---------------------------------------------------------------------------
// Kernel 3: merge the SPLIT partials.
// ---------------------------------------------------------------------------
__global__ __launch_bounds__(256)
void combine_kernel(const bf16* __restrict__ opart,
                    const float* __restrict__ mpart,
                    const float* __restrict__ lpart,
                    float* __restrict__ out)
{
    const int t   = threadIdx.x;
    const int row = blockIdx.x * 16 + (t >> 4);
    const int c0  = (t & 15) * 8;

    float ms[SPLIT], ls[SPLIT];
    float mstar = -INFINITY;
    #pragma unroll
    for (int s = 0; s < SPLIT; ++s) {
        ms[s] = mpart[(size_t)s * N_TOK + row];
        ls[s] = lpart[(size_t)s * N_TOK + row];
        mstar = fmaxf(mstar, ms[s]);
    }
    float acc[8] = {};
    float L = 0.f;
    #pragma unroll
    for (int s = 0; s < SPLIT; ++s) {
        float w = __expf(ms[s] - mstar);
        L += w * ls[s];
        bf16x8 o = *(const bf16x8*)&opart[((size_t)s * N_TOK + row) * D_H + c0];
        #pragma unroll
        for (int j = 0; j < 8; ++j)
            acc[j] += w * (float)o[j];
    }
    float inv = 1.f / L;
    float* dst = &out[(size_t)row * D_H + c0];
    *(float4*)(dst + 0) = make_float4(acc[0] * inv, acc[1] * inv,
                                      acc[2] * inv, acc[3] * inv);
    *(float4*)(dst + 4) = make_float4(acc[4] * inv, acc[5] * inv,
                                      acc[6] * inv, acc[7] * inv);
}

// ---------------------------------------------------------------------------
extern "C" void kernel_launch(void* const* d_in, const int* in_sizes, int n_in,
                              void* d_out, int out_size, void* d_ws, size_t ws_size,
                              hipStream_t stream) {
    const float* x  = (const float*)d_in[0];
    const float* Wq = (const float*)d_in[1];
    const float* Wk = (const float*)d_in[2];
    const float* Wv = (const float*)d_in[3];
    float* out = (float*)d_out;

    // ws (bf16): qh,ql row-major; khf,klf,vtf fragment order (each N*128);
    //            opart [8][N][128]; fp32 mpart/lpart [8][N].  ~27 MB.
    bf16* wsb = (bf16*)d_ws;
    const size_t SZ = (size_t)N_TOK * D_H;
    bf16* qh  = wsb;
    bf16* ql  = wsb + SZ;
    bf16* khf = wsb + 2 * SZ;
    bf16* klf = wsb + 3 * SZ;
    bf16* vtf = wsb + 4 * SZ;
    bf16* opart = wsb + 5 * SZ;
    float* mpart = (float*)(wsb + (5 + SPLIT) * SZ);
    float* lpart = mpart + (size_t)SPLIT * N_TOK;

    qkv_kernel<<<dim3(N_TOK / PJ_BM, 3), 256, 0, stream>>>(x, Wq, Wk, Wv,
                                                           qh, ql, khf, klf, vtf);
    flash_kernel<<<dim3(N_TOK / BQ, SPLIT), 256, 0, stream>>>(qh, ql, khf, klf, vtf,
                                                              opart, mpart, lpart);
    combine_kernel<<<dim3(N_TOK / 16), 256, 0, stream>>>(opart, mpart, lpart, out);
}